// Round 1
// baseline (462.205 us; speedup 1.0000x reference)
//
#include <hip/hip_runtime.h>
#include <hip/hip_bf16.h>
#include <stdint.h>

#define IN_F 784
#define OUT_F 1000
#define CH 16                    // [silu, b0..b12, 0, 0]
#define KDIM (IN_F * CH)         // 12544
#define MDIM 8192
#define NPAD 1024
#define KSTEPS (KDIM / 64)       // 196

typedef __attribute__((ext_vector_type(8))) short bf16x8;
typedef __attribute__((ext_vector_type(4))) float f32x4;

__device__ __forceinline__ unsigned short f2bf(float f) {
    unsigned u = __float_as_uint(f);
    u = (u + 0x7FFFu + ((u >> 16) & 1u)) >> 16;   // RNE
    return (unsigned short)u;
}
__device__ __forceinline__ unsigned pack2(float lo, float hi) {
    return (unsigned)f2bf(lo) | ((unsigned)f2bf(hi) << 16);
}

// ---------------- prep_A: x -> A bf16 [8192][12544] ----------------
__global__ void prep_A(const float* __restrict__ X, unsigned short* __restrict__ A) {
    int tid = blockIdx.x * 256 + threadIdx.x;
    int b = tid / IN_F;
    int i = tid - b * IN_F;
    float x = X[tid];
    float s = x / (1.0f + __expf(-x));          // silu
    float tf = x * 10.0f;
    float cf = floorf(tf);
    cf = fminf(fmaxf(cf, 0.0f), 9.0f);
    int c = (int)cf;
    float u = tf - cf;
    float u2 = u * u, u3 = u2 * u;
    float om = 1.0f - u;
    const float s6 = 1.0f / 6.0f;
    float b0 = om * om * om * s6;
    float b1 = (3.0f * u3 - 6.0f * u2 + 4.0f) * s6;
    float b2 = (-3.0f * u3 + 3.0f * u2 + 3.0f * u + 1.0f) * s6;
    float b3 = u3 * s6;
    float v[16];
    v[0] = s;
    #pragma unroll
    for (int k = 0; k < 13; ++k) {              // static indices only (no scratch)
        float val = (k == c)     ? b0 : 0.0f;
        val       = (k == c + 1) ? b1 : val;
        val       = (k == c + 2) ? b2 : val;
        val       = (k == c + 3) ? b3 : val;
        v[1 + k] = val;
    }
    v[14] = 0.0f; v[15] = 0.0f;
    unsigned w[8];
    #pragma unroll
    for (int j = 0; j < 8; ++j) w[j] = pack2(v[2 * j], v[2 * j + 1]);
    uint4* dst = (uint4*)(A + (size_t)b * KDIM + (size_t)i * CH);
    dst[0] = make_uint4(w[0], w[1], w[2], w[3]);
    dst[1] = make_uint4(w[4], w[5], w[6], w[7]);
}

// ---------------- prep_W: weights -> W bf16 [1024][12544] ----------------
__global__ void prep_W(const float* __restrict__ BW, const float* __restrict__ SW,
                       const float* __restrict__ SC, unsigned short* __restrict__ Wm) {
    int tid = blockIdx.x * 256 + threadIdx.x;
    int o = tid / IN_F;
    int i = tid - o * IN_F;
    unsigned w[8];
    if (o < OUT_F) {
        float bw = BW[o * IN_F + i];
        float sc = SC[o * IN_F + i];
        const float* swp = SW + (size_t)(o * IN_F + i) * 13;
        float v[16];
        v[0] = bw;
        #pragma unroll
        for (int g = 0; g < 13; ++g) v[1 + g] = swp[g] * sc;
        v[14] = 0.0f; v[15] = 0.0f;
        #pragma unroll
        for (int j = 0; j < 8; ++j) w[j] = pack2(v[2 * j], v[2 * j + 1]);
    } else {
        #pragma unroll
        for (int j = 0; j < 8; ++j) w[j] = 0u;
    }
    uint4* dst = (uint4*)(Wm + (size_t)o * KDIM + (size_t)i * CH);
    dst[0] = make_uint4(w[0], w[1], w[2], w[3]);
    dst[1] = make_uint4(w[4], w[5], w[6], w[7]);
}

// ---------------- GEMM: logits = A * W^T (m97-style 128x128x64) ----------------
__global__ void __launch_bounds__(256) kan_gemm(const unsigned short* __restrict__ A,
                                                const unsigned short* __restrict__ W,
                                                float* __restrict__ out) {
    __shared__ __align__(16) unsigned char smem[32768];   // A: [0,16K) B: [16K,32K), 128 rows x 128B
    const int t = threadIdx.x;
    const int bid = blockIdx.x;
    const int mb = bid >> 3, nb = bid & 7;
    const int bRow = mb * 128, bCol = nb * 128;
    const int w = t >> 6;
    const int lane = t & 63;
    const int lrow = lane & 15;
    const int lk = lane >> 4;         // 0..3
    const int sx = lrow & 7;          // row-XOR for swizzled reads
    const int r8 = t >> 3;            // 0..31 (staging row within issue group)
    const int p = t & 7;              // staging phys chunk
    const int wm = w >> 1, wn = w & 1;

    const char* Ab = (const char*)A;
    const char* Wb = (const char*)W;

    f32x4 acc[4][4];
    #pragma unroll
    for (int m = 0; m < 4; ++m)
        #pragma unroll
        for (int n = 0; n < 4; ++n)
            acc[m][n] = (f32x4){0.f, 0.f, 0.f, 0.f};

    for (int ks = 0; ks < KSTEPS; ++ks) {
        const int k0 = ks * 64;
        // stage A tile: LDS linear dest, pre-swizzled global source (chunk p holds logical p^(r&7))
        #pragma unroll
        for (int it = 0; it < 4; ++it) {
            int r = it * 32 + r8;
            int sc = p ^ (r & 7);
            const char* src = Ab + ((size_t)(bRow + r) * KDIM + k0) * 2 + sc * 16;
            __builtin_amdgcn_global_load_lds(
                (const __attribute__((address_space(1))) char*)src,
                (__attribute__((address_space(3))) char*)&smem[it * 4096 + w * 1024],
                16, 0, 0);
        }
        // stage B tile
        #pragma unroll
        for (int it = 0; it < 4; ++it) {
            int r = it * 32 + r8;
            int sc = p ^ (r & 7);
            const char* src = Wb + ((size_t)(bCol + r) * KDIM + k0) * 2 + sc * 16;
            __builtin_amdgcn_global_load_lds(
                (const __attribute__((address_space(1))) char*)src,
                (__attribute__((address_space(3))) char*)&smem[16384 + it * 4096 + w * 1024],
                16, 0, 0);
        }
        __syncthreads();   // compiler drains vmcnt(0) before s_barrier

        #pragma unroll
        for (int kk = 0; kk < 2; ++kk) {
            bf16x8 af[4], bfr[4];
            #pragma unroll
            for (int m = 0; m < 4; ++m) {
                int row = wm * 64 + m * 16 + lrow;
                int ch = (kk * 4 + lk) ^ sx;
                af[m] = *(const bf16x8*)&smem[row * 128 + ch * 16];
            }
            #pragma unroll
            for (int n = 0; n < 4; ++n) {
                int row = wn * 64 + n * 16 + lrow;
                int ch = (kk * 4 + lk) ^ sx;
                bfr[n] = *(const bf16x8*)&smem[16384 + row * 128 + ch * 16];
            }
            #pragma unroll
            for (int m = 0; m < 4; ++m)
                #pragma unroll
                for (int n = 0; n < 4; ++n)
                    acc[m][n] = __builtin_amdgcn_mfma_f32_16x16x32_bf16(af[m], bfr[n], acc[m][n], 0, 0, 0);
        }
        __syncthreads();   // protect LDS before next stage
    }

    // epilogue: C/D layout col = lane&15, row = (lane>>4)*4 + j  [m89-verified]
    #pragma unroll
    for (int m = 0; m < 4; ++m) {
        int grow0 = bRow + wm * 64 + m * 16 + lk * 4;
        #pragma unroll
        for (int n = 0; n < 4; ++n) {
            int gcol = bCol + wn * 64 + n * 16 + lrow;
            if (gcol < OUT_F) {
                #pragma unroll
                for (int j = 0; j < 4; ++j)
                    out[(size_t)(grow0 + j) * OUT_F + gcol] = acc[m][n][j];
            }
        }
    }
}

// ---------------- log-softmax, in-place on d_out rows of 1000 ----------------
__global__ void logsoftmax_inplace(float* __restrict__ out) {
    const int b = blockIdx.x;
    float* row = out + (size_t)b * OUT_F;
    const int t = threadIdx.x;
    const int ln = t & 63, wv = t >> 6;
    float v[4];
    #pragma unroll
    for (int j = 0; j < 4; ++j) {
        int idx = t + 256 * j;
        v[j] = (idx < OUT_F) ? row[idx] : -1e30f;
    }
    float m = fmaxf(fmaxf(v[0], v[1]), fmaxf(v[2], v[3]));
    #pragma unroll
    for (int off = 32; off > 0; off >>= 1) m = fmaxf(m, __shfl_xor(m, off, 64));
    __shared__ float red[4];
    if (ln == 0) red[wv] = m;
    __syncthreads();
    m = fmaxf(fmaxf(red[0], red[1]), fmaxf(red[2], red[3]));
    float s = 0.f;
    #pragma unroll
    for (int j = 0; j < 4; ++j) {
        int idx = t + 256 * j;
        if (idx < OUT_F) s += __expf(v[j] - m);
    }
    #pragma unroll
    for (int off = 32; off > 0; off >>= 1) s += __shfl_xor(s, off, 64);
    __syncthreads();
    if (ln == 0) red[wv] = s;
    __syncthreads();
    s = red[0] + red[1] + red[2] + red[3];
    float lse = m + logf(s);
    #pragma unroll
    for (int j = 0; j < 4; ++j) {
        int idx = t + 256 * j;
        if (idx < OUT_F) row[idx] = v[j] - lse;
    }
}

extern "C" void kernel_launch(void* const* d_in, const int* in_sizes, int n_in,
                              void* d_out, int out_size, void* d_ws, size_t ws_size,
                              hipStream_t stream) {
    const float* x  = (const float*)d_in[0];   // 8192*784
    const float* bw = (const float*)d_in[1];   // 1000*784
    const float* sw = (const float*)d_in[2];   // 1000*784*13
    const float* sc = (const float*)d_in[3];   // 1000*784
    float* out = (float*)d_out;                // 8192*1000 f32

    unsigned short* A  = (unsigned short*)d_ws;                                   // 205.5 MB
    unsigned short* Wm = (unsigned short*)((char*)d_ws + (size_t)MDIM * KDIM * 2); // 25.7 MB

    prep_A<<<dim3(MDIM * IN_F / 256), 256, 0, stream>>>(x, A);
    prep_W<<<dim3(NPAD * IN_F / 256), 256, 0, stream>>>(bw, sw, sc, Wm);
    kan_gemm<<<dim3((MDIM / 128) * (NPAD / 128)), 256, 0, stream>>>(A, Wm, out);
    logsoftmax_inplace<<<dim3(MDIM), 256, 0, stream>>>(out);
}

// Round 3
// 441.986 us; speedup vs baseline: 1.0457x; 1.0457x over previous
//
#include <hip/hip_runtime.h>
#include <hip/hip_bf16.h>
#include <stdint.h>

#define IN_F 784
#define OUT_F 1000
#define CH 16                    // [silu, b0..b12, 0, 0]
#define KDIM (IN_F * CH)         // 12544
#define MDIM 8192
#define NPAD 1024
#define KSTEPS (KDIM / 64)       // 196
#define KHALF (KSTEPS / 2)       // 98

typedef __attribute__((ext_vector_type(8))) short bf16x8;
typedef __attribute__((ext_vector_type(4))) float f32x4;

__device__ __forceinline__ unsigned short f2bf(float f) {
    unsigned u = __float_as_uint(f);
    u = (u + 0x7FFFu + ((u >> 16) & 1u)) >> 16;   // RNE
    return (unsigned short)u;
}
__device__ __forceinline__ unsigned pack2(float lo, float hi) {
    return (unsigned)f2bf(lo) | ((unsigned)f2bf(hi) << 16);
}

// ---------------- prep_A: x -> A bf16 [8192][12544] ----------------
__global__ void prep_A(const float* __restrict__ X, unsigned short* __restrict__ A) {
    int tid = blockIdx.x * 256 + threadIdx.x;
    int b = tid / IN_F;
    int i = tid - b * IN_F;
    float x = X[tid];
    float s = x / (1.0f + __expf(-x));          // silu
    float tf = x * 10.0f;
    float cf = floorf(tf);
    cf = fminf(fmaxf(cf, 0.0f), 9.0f);
    int c = (int)cf;
    float u = tf - cf;
    float u2 = u * u, u3 = u2 * u;
    float om = 1.0f - u;
    const float s6 = 1.0f / 6.0f;
    float b0 = om * om * om * s6;
    float b1 = (3.0f * u3 - 6.0f * u2 + 4.0f) * s6;
    float b2 = (-3.0f * u3 + 3.0f * u2 + 3.0f * u + 1.0f) * s6;
    float b3 = u3 * s6;
    float v[16];
    v[0] = s;
    #pragma unroll
    for (int k = 0; k < 13; ++k) {              // static indices only (no scratch)
        float val = (k == c)     ? b0 : 0.0f;
        val       = (k == c + 1) ? b1 : val;
        val       = (k == c + 2) ? b2 : val;
        val       = (k == c + 3) ? b3 : val;
        v[1 + k] = val;
    }
    v[14] = 0.0f; v[15] = 0.0f;
    unsigned w[8];
    #pragma unroll
    for (int j = 0; j < 8; ++j) w[j] = pack2(v[2 * j], v[2 * j + 1]);
    uint4* dst = (uint4*)(A + (size_t)b * KDIM + (size_t)i * CH);
    dst[0] = make_uint4(w[0], w[1], w[2], w[3]);
    dst[1] = make_uint4(w[4], w[5], w[6], w[7]);
}

// ---------------- prep_W: weights -> W bf16 [1024][12544] ----------------
__global__ void prep_W(const float* __restrict__ BW, const float* __restrict__ SW,
                       const float* __restrict__ SC, unsigned short* __restrict__ Wm) {
    int tid = blockIdx.x * 256 + threadIdx.x;
    int o = tid / IN_F;
    int i = tid - o * IN_F;
    unsigned w[8];
    if (o < OUT_F) {
        float bw = BW[o * IN_F + i];
        float sc = SC[o * IN_F + i];
        const float* swp = SW + (size_t)(o * IN_F + i) * 13;
        float v[16];
        v[0] = bw;
        #pragma unroll
        for (int g = 0; g < 13; ++g) v[1 + g] = swp[g] * sc;
        v[14] = 0.0f; v[15] = 0.0f;
        #pragma unroll
        for (int j = 0; j < 8; ++j) w[j] = pack2(v[2 * j], v[2 * j + 1]);
    } else {
        #pragma unroll
        for (int j = 0; j < 8; ++j) w[j] = 0u;
    }
    uint4* dst = (uint4*)(Wm + (size_t)o * KDIM + (size_t)i * CH);
    dst[0] = make_uint4(w[0], w[1], w[2], w[3]);
    dst[1] = make_uint4(w[4], w[5], w[6], w[7]);
}

// ---------------- GEMM: logits = A * W^T, 128x128 tile, in-block split-K ----------------
// 512 threads = 8 waves. Waves 0-3: K-half 0; waves 4-7: K-half 1.
// Each K-group has its own 32KB LDS pair (A+B tile); 64KB total -> 2 blocks/CU = 16 waves/CU.
__global__ void __launch_bounds__(512, 4) kan_gemm(const unsigned short* __restrict__ A,
                                                   const unsigned short* __restrict__ W,
                                                   float* __restrict__ out) {
    __shared__ __align__(16) unsigned char smem[65536];
    const int t = threadIdx.x;
    // bijective XCD swizzle: 512 blocks, 8 XCDs, 64 contiguous per XCD
    const int bid = blockIdx.x;
    const int sid = (bid & 7) * 64 + (bid >> 3);
    const int mb = sid >> 3, nb = sid & 7;
    const int bRow = mb * 128, bCol = nb * 128;

    const int g  = t >> 8;            // K-group 0/1
    const int tg = t & 255;           // thread-in-group
    const int wg = tg >> 6;           // wave-in-group 0..3
    const int lane = t & 63;
    const int lrow = lane & 15;
    const int lk = lane >> 4;         // 0..3
    const int sx = lrow & 7;          // row-XOR for swizzled reads
    const int r8 = tg >> 3;           // 0..31 staging row-in-issue-group
    const int p = tg & 7;             // staging phys chunk
    const int wm = wg >> 1, wn = wg & 1;
    const int sbase = g * 32768;      // group LDS base: A at +0, B at +16384

    const char* Ab = (const char*)A;
    const char* Wb = (const char*)W;

    f32x4 acc[4][4];
    #pragma unroll
    for (int m = 0; m < 4; ++m)
        #pragma unroll
        for (int n = 0; n < 4; ++n)
            acc[m][n] = (f32x4){0.f, 0.f, 0.f, 0.f};

    for (int ks = 0; ks < KHALF; ++ks) {
        const int k0 = (g * KHALF + ks) * 64;
        // stage A tile (LDS linear dest, pre-swizzled global source)
        #pragma unroll
        for (int it = 0; it < 4; ++it) {
            int r = it * 32 + r8;
            int sc = p ^ (r & 7);
            const char* src = Ab + ((size_t)(bRow + r) * KDIM + k0) * 2 + sc * 16;
            __builtin_amdgcn_global_load_lds(
                (const __attribute__((address_space(1))) char*)src,
                (__attribute__((address_space(3))) char*)&smem[sbase + it * 4096 + wg * 1024],
                16, 0, 0);
        }
        // stage B tile
        #pragma unroll
        for (int it = 0; it < 4; ++it) {
            int r = it * 32 + r8;
            int sc = p ^ (r & 7);
            const char* src = Wb + ((size_t)(bCol + r) * KDIM + k0) * 2 + sc * 16;
            __builtin_amdgcn_global_load_lds(
                (const __attribute__((address_space(1))) char*)src,
                (__attribute__((address_space(3))) char*)&smem[sbase + 16384 + it * 4096 + wg * 1024],
                16, 0, 0);
        }
        __syncthreads();

        #pragma unroll
        for (int kk = 0; kk < 2; ++kk) {
            bf16x8 af[4], bfr[4];
            #pragma unroll
            for (int m = 0; m < 4; ++m) {
                int row = wm * 64 + m * 16 + lrow;
                int ch = (kk * 4 + lk) ^ sx;
                af[m] = *(const bf16x8*)&smem[sbase + row * 128 + ch * 16];
            }
            #pragma unroll
            for (int n = 0; n < 4; ++n) {
                int row = wn * 64 + n * 16 + lrow;
                int ch = (kk * 4 + lk) ^ sx;
                bfr[n] = *(const bf16x8*)&smem[sbase + 16384 + row * 128 + ch * 16];
            }
            #pragma unroll
            for (int m = 0; m < 4; ++m)
                #pragma unroll
                for (int n = 0; n < 4; ++n)
                    acc[m][n] = __builtin_amdgcn_mfma_f32_16x16x32_bf16(af[m], bfr[n], acc[m][n], 0, 0, 0);
        }
        __syncthreads();
    }

    // ---- combine the two K-halves through LDS (conflict-free: lane-contiguous 1KB rows) ----
    if (g == 1) {
        #pragma unroll
        for (int m = 0; m < 4; ++m)
            #pragma unroll
            for (int n = 0; n < 4; ++n)
                *(f32x4*)&smem[wg * 16384 + (m * 4 + n) * 1024 + lane * 16] = acc[m][n];
    }
    __syncthreads();
    if (g == 0) {
        #pragma unroll
        for (int m = 0; m < 4; ++m)
            #pragma unroll
            for (int n = 0; n < 4; ++n) {
                f32x4 o = *(const f32x4*)&smem[wg * 16384 + (m * 4 + n) * 1024 + lane * 16];
                acc[m][n] += o;
            }
        // epilogue: C/D layout col = lane&15, row = (lane>>4)*4 + j  [m89-verified]
        #pragma unroll
        for (int m = 0; m < 4; ++m) {
            int grow0 = bRow + wm * 64 + m * 16 + lk * 4;
            #pragma unroll
            for (int n = 0; n < 4; ++n) {
                int gcol = bCol + wn * 64 + n * 16 + lrow;
                if (gcol < OUT_F) {
                    #pragma unroll
                    for (int j = 0; j < 4; ++j)
                        out[(size_t)(grow0 + j) * OUT_F + gcol] = acc[m][n][j];
                }
            }
        }
    }
}

// ---------------- log-softmax, in-place on d_out rows of 1000 ----------------
__global__ void logsoftmax_inplace(float* __restrict__ out) {
    const int b = blockIdx.x;
    float* row = out + (size_t)b * OUT_F;
    const int t = threadIdx.x;
    const int ln = t & 63, wv = t >> 6;
    float v[4];
    #pragma unroll
    for (int j = 0; j < 4; ++j) {
        int idx = t + 256 * j;
        v[j] = (idx < OUT_F) ? row[idx] : -1e30f;
    }
    float m = fmaxf(fmaxf(v[0], v[1]), fmaxf(v[2], v[3]));
    #pragma unroll
    for (int off = 32; off > 0; off >>= 1) m = fmaxf(m, __shfl_xor(m, off, 64));
    __shared__ float red[4];
    if (ln == 0) red[wv] = m;
    __syncthreads();
    m = fmaxf(fmaxf(red[0], red[1]), fmaxf(red[2], red[3]));
    float s = 0.f;
    #pragma unroll
    for (int j = 0; j < 4; ++j) {
        int idx = t + 256 * j;
        if (idx < OUT_F) s += __expf(v[j] - m);
    }
    #pragma unroll
    for (int off = 32; off > 0; off >>= 1) s += __shfl_xor(s, off, 64);
    __syncthreads();
    if (ln == 0) red[wv] = s;
    __syncthreads();
    s = red[0] + red[1] + red[2] + red[3];
    float lse = m + logf(s);
    #pragma unroll
    for (int j = 0; j < 4; ++j) {
        int idx = t + 256 * j;
        if (idx < OUT_F) row[idx] = v[j] - lse;
    }
}

extern "C" void kernel_launch(void* const* d_in, const int* in_sizes, int n_in,
                              void* d_out, int out_size, void* d_ws, size_t ws_size,
                              hipStream_t stream) {
    const float* x  = (const float*)d_in[0];   // 8192*784
    const float* bw = (const float*)d_in[1];   // 1000*784
    const float* sw = (const float*)d_in[2];   // 1000*784*13
    const float* sc = (const float*)d_in[3];   // 1000*784
    float* out = (float*)d_out;                // 8192*1000 f32

    unsigned short* A  = (unsigned short*)d_ws;                                    // 205.5 MB
    unsigned short* Wm = (unsigned short*)((char*)d_ws + (size_t)MDIM * KDIM * 2); // 25.7 MB

    prep_A<<<dim3(MDIM * IN_F / 256), 256, 0, stream>>>(x, A);
    prep_W<<<dim3(NPAD * IN_F / 256), 256, 0, stream>>>(bw, sw, sc, Wm);
    kan_gemm<<<dim3((MDIM / 128) * (NPAD / 128)), 512, 0, stream>>>(A, Wm, out);
    logsoftmax_inplace<<<dim3(MDIM), 256, 0, stream>>>(out);
}

// Round 6
// 373.390 us; speedup vs baseline: 1.2379x; 1.1837x over previous
//
#include <hip/hip_runtime.h>
#include <hip/hip_bf16.h>
#include <stdint.h>

#define IN_F 784
#define OUT_F 1000
#define CH 16                    // [silu, b0..b12, 0, 0]
#define KDIM (IN_F * CH)         // 12544
#define MDIM 8192
#define NPAD 1024
#define NT (KDIM / 64)           // 196 K-tiles of BK=64
#define BUFSZ 49152              // A-tile 32KB + B-tile 16KB

typedef __attribute__((ext_vector_type(8))) short bf16x8;
typedef __attribute__((ext_vector_type(4))) float f32x4;

__device__ __forceinline__ unsigned short f2bf(float f) {
    unsigned u = __float_as_uint(f);
    u = (u + 0x7FFFu + ((u >> 16) & 1u)) >> 16;   // RNE
    return (unsigned short)u;
}
__device__ __forceinline__ unsigned pack2(float lo, float hi) {
    return (unsigned)f2bf(lo) | ((unsigned)f2bf(hi) << 16);
}

// ---------------- prep_A: x -> A bf16 [8192][12544] ----------------
__global__ void prep_A(const float* __restrict__ X, unsigned short* __restrict__ A) {
    int tid = blockIdx.x * 256 + threadIdx.x;
    int b = tid / IN_F;
    int i = tid - b * IN_F;
    float x = X[tid];
    float s = x / (1.0f + __expf(-x));          // silu
    float tf = x * 10.0f;
    float cf = floorf(tf);
    cf = fminf(fmaxf(cf, 0.0f), 9.0f);
    int c = (int)cf;
    float u = tf - cf;
    float u2 = u * u, u3 = u2 * u;
    float om = 1.0f - u;
    const float s6 = 1.0f / 6.0f;
    float b0 = om * om * om * s6;
    float b1 = (3.0f * u3 - 6.0f * u2 + 4.0f) * s6;
    float b2 = (-3.0f * u3 + 3.0f * u2 + 3.0f * u + 1.0f) * s6;
    float b3 = u3 * s6;
    float v[16];
    v[0] = s;
    #pragma unroll
    for (int k = 0; k < 13; ++k) {              // static indices only (no scratch)
        float val = (k == c)     ? b0 : 0.0f;
        val       = (k == c + 1) ? b1 : val;
        val       = (k == c + 2) ? b2 : val;
        val       = (k == c + 3) ? b3 : val;
        v[1 + k] = val;
    }
    v[14] = 0.0f; v[15] = 0.0f;
    unsigned w[8];
    #pragma unroll
    for (int j = 0; j < 8; ++j) w[j] = pack2(v[2 * j], v[2 * j + 1]);
    uint4* dst = (uint4*)(A + (size_t)b * KDIM + (size_t)i * CH);
    dst[0] = make_uint4(w[0], w[1], w[2], w[3]);
    dst[1] = make_uint4(w[4], w[5], w[6], w[7]);
}

// ---------------- prep_W: weights -> W bf16 [1024][12544] ----------------
__global__ void prep_W(const float* __restrict__ BW, const float* __restrict__ SW,
                       const float* __restrict__ SC, unsigned short* __restrict__ Wm) {
    int tid = blockIdx.x * 256 + threadIdx.x;
    int o = tid / IN_F;
    int i = tid - o * IN_F;
    unsigned w[8];
    if (o < OUT_F) {
        float bw = BW[o * IN_F + i];
        float sc = SC[o * IN_F + i];
        const float* swp = SW + (size_t)(o * IN_F + i) * 13;
        float v[16];
        v[0] = bw;
        #pragma unroll
        for (int g = 0; g < 13; ++g) v[1 + g] = swp[g] * sc;
        v[14] = 0.0f; v[15] = 0.0f;
        #pragma unroll
        for (int j = 0; j < 8; ++j) w[j] = pack2(v[2 * j], v[2 * j + 1]);
    } else {
        #pragma unroll
        for (int j = 0; j < 8; ++j) w[j] = 0u;
    }
    uint4* dst = (uint4*)(Wm + (size_t)o * KDIM + (size_t)i * CH);
    dst[0] = make_uint4(w[0], w[1], w[2], w[3]);
    dst[1] = make_uint4(w[4], w[5], w[6], w[7]);
}

// ---------------- GEMM: logits = A * W^T ----------------
// BM=256, BN=128, BK=64. 512 threads = 8 waves (4M x 2N), per-wave 64x64 out.
// 3 LDS buffers (48KB each = 144KB), depth-2 prefetch, counted vmcnt(6),
// ONE raw s_barrier per K-tile (T3/T4: loads stay in flight across barriers).
__global__ void __launch_bounds__(512, 2) kan_gemm(const unsigned short* __restrict__ A,
                                                   const unsigned short* __restrict__ W,
                                                   float* __restrict__ out) {
    __shared__ __align__(16) unsigned char smem[3 * BUFSZ];   // 144 KB
    const int t = threadIdx.x;
    const int bid = blockIdx.x;
    // bijective XCD swizzle: 256 blocks, 8 XCDs, 32 contiguous sids per XCD.
    // Within an XCD: 4 consecutive M-panels x all 8 N-panels -> A fetched from
    // HBM once chip-wide (8 same-mb blocks share one XCD L2), B L3-served.
    const int sid = ((bid & 7) << 5) + (bid >> 3);
    const int mb = sid >> 3, nb = sid & 7;
    const int bRow = mb << 8, bCol = nb << 7;

    const int lane = t & 63;
    const int w    = t >> 6;
    const int lrow = lane & 15;
    const int lk   = lane >> 4;        // 0..3
    const int sx   = lrow & 7;         // row-XOR for swizzled reads
    const int wm   = w >> 1, wn = w & 1;
    const int r8   = t >> 3;           // 0..63 staging row
    const int p    = t & 7;            // staging phys 16B chunk
    const int lch  = p ^ (r8 & 7);     // logical chunk this thread fetches

    // per-thread staging source bases (K-offset added per tile)
    const char* srcA[4];
    const char* srcB[2];
    #pragma unroll
    for (int it = 0; it < 4; ++it)
        srcA[it] = (const char*)A + ((size_t)(bRow + it * 64 + r8) * KDIM) * 2 + lch * 16;
    #pragma unroll
    for (int it = 0; it < 2; ++it)
        srcB[it] = (const char*)W + ((size_t)(bCol + it * 64 + r8) * KDIM) * 2 + lch * 16;

    auto stage = [&](int kt, int buf) {
        const size_t ko = (size_t)kt << 7;           // kt * 128 bytes
        const unsigned db = buf * BUFSZ + t * 16;    // linear LDS dest (wave-uniform base + lane*16)
        #pragma unroll
        for (int it = 0; it < 4; ++it)
            __builtin_amdgcn_global_load_lds(
                (const __attribute__((address_space(1))) char*)(srcA[it] + ko),
                (__attribute__((address_space(3))) char*)&smem[db + it * 8192],
                16, 0, 0);
        #pragma unroll
        for (int it = 0; it < 2; ++it)
            __builtin_amdgcn_global_load_lds(
                (const __attribute__((address_space(1))) char*)(srcB[it] + ko),
                (__attribute__((address_space(3))) char*)&smem[db + 32768 + it * 8192],
                16, 0, 0);
    };

    f32x4 acc[4][4];
    #pragma unroll
    for (int m = 0; m < 4; ++m)
        #pragma unroll
        for (int n = 0; n < 4; ++n)
            acc[m][n] = (f32x4){0.f, 0.f, 0.f, 0.f};

    // prologue: tiles 0,1 in flight (12 loads/thread outstanding)
    stage(0, 0);
    stage(1, 1);

    int cur = 0;   // buffer holding tile kt
    int nbf = 2;   // buffer for tile kt+2
    for (int kt = 0; kt < NT; ++kt) {
        // tile kt's 6 loads are the OLDEST outstanding; leave tile kt+1's in flight.
        if (kt < NT - 1) asm volatile("s_waitcnt vmcnt(6)" ::: "memory");
        else             asm volatile("s_waitcnt vmcnt(0)" ::: "memory");
        __builtin_amdgcn_s_barrier();       // all waves: tile kt visible; buf nbf free
        asm volatile("" ::: "memory");

        const unsigned char* Abuf = &smem[cur * BUFSZ];
        const unsigned char* Bbuf = Abuf + 32768;
        bf16x8 af[4][2], bfr[4][2];
        #pragma unroll
        for (int m = 0; m < 4; ++m) {
            const int row = (wm << 6) + (m << 4) + lrow;
            #pragma unroll
            for (int kk = 0; kk < 2; ++kk)
                af[m][kk] = *(const bf16x8*)&Abuf[row * 128 + (((kk << 2) + lk) ^ sx) * 16];
        }
        #pragma unroll
        for (int n = 0; n < 4; ++n) {
            const int row = (wn << 6) + (n << 4) + lrow;
            #pragma unroll
            for (int kk = 0; kk < 2; ++kk)
                bfr[n][kk] = *(const bf16x8*)&Bbuf[row * 128 + (((kk << 2) + lk) ^ sx) * 16];
        }

        if (kt + 2 < NT) stage(kt + 2, nbf);   // issue next-next tile; lands any time ≥ barrier

        __builtin_amdgcn_s_setprio(1);
        #pragma unroll
        for (int m = 0; m < 4; ++m)
            #pragma unroll
            for (int n = 0; n < 4; ++n) {
                acc[m][n] = __builtin_amdgcn_mfma_f32_16x16x32_bf16(af[m][0], bfr[n][0], acc[m][n], 0, 0, 0);
                acc[m][n] = __builtin_amdgcn_mfma_f32_16x16x32_bf16(af[m][1], bfr[n][1], acc[m][n], 0, 0, 0);
            }
        __builtin_amdgcn_s_setprio(0);

        cur = (cur == 2) ? 0 : cur + 1;
        nbf = (nbf == 2) ? 0 : nbf + 1;
    }

    // epilogue: C/D layout col = lane&15, row = (lane>>4)*4 + j  [m89-verified]
    #pragma unroll
    for (int m = 0; m < 4; ++m) {
        int grow0 = bRow + (wm << 6) + (m << 4) + (lk << 2);
        #pragma unroll
        for (int n = 0; n < 4; ++n) {
            int gcol = bCol + (wn << 6) + (n << 4) + lrow;
            if (gcol < OUT_F) {
                #pragma unroll
                for (int j = 0; j < 4; ++j)
                    out[(size_t)(grow0 + j) * OUT_F + gcol] = acc[m][n][j];
            }
        }
    }
}

// ---------------- log-softmax, in-place on d_out rows of 1000 ----------------
__global__ void logsoftmax_inplace(float* __restrict__ out) {
    const int b = blockIdx.x;
    float* row = out + (size_t)b * OUT_F;
    const int t = threadIdx.x;
    const int ln = t & 63, wv = t >> 6;
    float v[4];
    #pragma unroll
    for (int j = 0; j < 4; ++j) {
        int idx = t + 256 * j;
        v[j] = (idx < OUT_F) ? row[idx] : -1e30f;
    }
    float m = fmaxf(fmaxf(v[0], v[1]), fmaxf(v[2], v[3]));
    #pragma unroll
    for (int off = 32; off > 0; off >>= 1) m = fmaxf(m, __shfl_xor(m, off, 64));
    __shared__ float red[4];
    if (ln == 0) red[wv] = m;
    __syncthreads();
    m = fmaxf(fmaxf(red[0], red[1]), fmaxf(red[2], red[3]));
    float s = 0.f;
    #pragma unroll
    for (int j = 0; j < 4; ++j) {
        int idx = t + 256 * j;
        if (idx < OUT_F) s += __expf(v[j] - m);
    }
    #pragma unroll
    for (int off = 32; off > 0; off >>= 1) s += __shfl_xor(s, off, 64);
    __syncthreads();
    if (ln == 0) red[wv] = s;
    __syncthreads();
    s = red[0] + red[1] + red[2] + red[3];
    float lse = m + logf(s);
    #pragma unroll
    for (int j = 0; j < 4; ++j) {
        int idx = t + 256 * j;
        if (idx < OUT_F) row[idx] = v[j] - lse;
    }
}

extern "C" void kernel_launch(void* const* d_in, const int* in_sizes, int n_in,
                              void* d_out, int out_size, void* d_ws, size_t ws_size,
                              hipStream_t stream) {
    const float* x  = (const float*)d_in[0];   // 8192*784
    const float* bw = (const float*)d_in[1];   // 1000*784
    const float* sw = (const float*)d_in[2];   // 1000*784*13
    const float* sc = (const float*)d_in[3];   // 1000*784
    float* out = (float*)d_out;                // 8192*1000 f32

    unsigned short* A  = (unsigned short*)d_ws;                                    // 205.5 MB
    unsigned short* Wm = (unsigned short*)((char*)d_ws + (size_t)MDIM * KDIM * 2); // 25.7 MB

    prep_A<<<dim3(MDIM * IN_F / 256), 256, 0, stream>>>(x, A);
    prep_W<<<dim3(NPAD * IN_F / 256), 256, 0, stream>>>(bw, sw, sc, Wm);
    kan_gemm<<<dim3((MDIM / 256) * (NPAD / 128)), 512, 0, stream>>>(A, Wm, out);
    logsoftmax_inplace<<<dim3(MDIM), 256, 0, stream>>>(out);
}